// Round 13
// baseline (101.140 us; speedup 1.0000x reference)
//
#include <hip/hip_runtime.h>
#include <hip/hip_bf16.h>
#include <stdint.h>

#define NH 16
#define HID 1024
#define HD 64
#define NB 4
#define SS 1024
#define MTOT (NB*SS)   // 4096

typedef __attribute__((ext_vector_type(8))) short bf16x8;
typedef __attribute__((ext_vector_type(4))) float f32x4;
typedef __attribute__((ext_vector_type(16))) float f32x16;

#define LOG2E 1.44269504088896f

__device__ __forceinline__ unsigned short f2bf(float f) {
  union { float f; unsigned u; } v; v.f = f;
  unsigned u = v.u;
  return (unsigned short)((u + 0x7FFFu + ((u >> 16) & 1u)) >> 16);
}

__device__ __forceinline__ unsigned cvtpk(float lo, float hi) {
  unsigned r;
  asm("v_cvt_pk_bf16_f32 %0, %1, %2" : "=v"(r) : "v"(lo), "v"(hi));
  return r;
}

__device__ __forceinline__ void pl32swap(unsigned &a, unsigned &b) {
  asm("v_permlane32_swap_b32 %0, %1" : "+v"(a), "+v"(b));
}

__device__ __forceinline__ float exp2fast(float x) {
  float r;
  asm("v_exp_f32 %0, %1" : "=v"(r) : "v"(x));
  return r;
}

__device__ __forceinline__ void async16(void* lds, const void* g) {
  __builtin_amdgcn_global_load_lds(
      (const __attribute__((address_space(1))) unsigned*)g,
      (__attribute__((address_space(3))) unsigned*)lds, 16, 0, 0);
}

// ---------------- fp32 -> bf16 conversion of X and W ----------------
__global__ void cvt_all(const float4* __restrict__ X,
                        const float4* __restrict__ Wq,
                        const float4* __restrict__ Wk,
                        const float4* __restrict__ Wv,
                        ushort4* __restrict__ Xb,
                        ushort4* __restrict__ Wb) {
  int i = blockIdx.x * 256 + threadIdx.x;   // 1835008 total
  const float4* src; ushort4* dst; int idx;
  if (i < (MTOT * HID / 4)) {
    src = X; dst = Xb; idx = i;
  } else {
    int j = i - (MTOT * HID / 4);
    int sel = j >> 18;
    idx = j & 262143;
    src = (sel == 0) ? Wq : (sel == 1) ? Wk : Wv;
    dst = Wb + (size_t)sel * 262144;
  }
  float4 v = src[idx];
  ushort4 o;
  o.x = f2bf(v.x); o.y = f2bf(v.y); o.z = f2bf(v.z); o.w = f2bf(v.w);
  dst[idx] = o;
}

// ---------------- fused QKV projection GEMM (R6 config, proven 45.5us) ----
// BK=32 TRIPLE-buffered, 1 barrier/step, STAGE after barrier, counted vmcnt.
// Q pre-scaled by 0.125*log2(e) so attention softmax runs in exp2 domain.
__global__ __launch_bounds__(256) void qkv_gemm(
    const ushort* __restrict__ Xb,    // [4096][1024] bf16
    const ushort* __restrict__ Wb,    // [3072][1024] bf16 (Wq|Wk|Wv)
    const float* __restrict__ bq,
    const float* __restrict__ bk,
    const float* __restrict__ bv,
    ushort* __restrict__ Q,           // [B*H][S][64]
    ushort* __restrict__ K,           // [B*H][S][64]
    ushort* __restrict__ Vt)          // [B*H][64][S]
{
  __shared__ __attribute__((aligned(16))) ushort Al[3][128 * 32]; // 3x8KB
  __shared__ __attribute__((aligned(16))) ushort Bl[3][128 * 32]; // 3x8KB

  int bid = blockIdx.x;               // 768 blocks
  int swz = (bid & 7) * 96 + (bid >> 3);  // XCD swizzle (768 % 8 == 0)
  const int nbn = 3072 / 128;         // 24
  int bm = swz / nbn, bn = swz % nbn;
  int m0 = bm * 128, n0 = bn * 128;

  int tid = threadIdx.x;
  int wave = tid >> 6, lane = tid & 63;
  int g = lane >> 4, c = lane & 15;
  int wr = wave >> 1, wc = wave & 1;  // 2x2 waves, each 64x64 output

  // staging: per K-step each thread issues 2 A-loads + 2 B-loads (16B).
  // LDS dest linear; bank swizzle via XOR on the GLOBAL 16B-chunk index.
  int srow = tid >> 2;                // 0..63
  int schunk = tid & 3;
  int ssw = (srow >> 1) & 3;
  const ushort* Asrc0 = Xb + (size_t)(m0 + srow) * 1024 + ((schunk ^ ssw) << 3);
  const ushort* Asrc1 = Xb + (size_t)(m0 + 64 + srow) * 1024 + ((schunk ^ ssw) << 3);
  const ushort* Bsrc0 = Wb + (size_t)(n0 + srow) * 1024 + ((schunk ^ ssw) << 3);
  const ushort* Bsrc1 = Wb + (size_t)(n0 + 64 + srow) * 1024 + ((schunk ^ ssw) << 3);
  int soff = srow * 64 + schunk * 16;

#define GSTAGE(bi) do {                                   \
    char* la_ = (char*)Al[bi]; char* lb_ = (char*)Bl[bi]; \
    async16(la_ + soff,        Asrc0);                    \
    async16(la_ + 4096 + soff, Asrc1);                    \
    async16(lb_ + soff,        Bsrc0);                    \
    async16(lb_ + 4096 + soff, Bsrc1);                    \
    Asrc0 += 32; Asrc1 += 32; Bsrc0 += 32; Bsrc1 += 32;   \
  } while (0)

  f32x4 acc[4][4] = {};
  int rsw = (c >> 1) & 3;             // read-side swizzle
  int ch = ((g ^ rsw) << 4);          // swizzled 16B chunk byte offset

  GSTAGE(0);                          // prologue: 2 steps in flight
  GSTAGE(1);

  int cur = 0, nxt = 2;
  for (int ks = 0; ks < 32; ++ks) {
    if (ks < 31) {
      asm volatile("s_waitcnt vmcnt(4)" ::: "memory");  // cur landed, next in flight
    } else {
      asm volatile("s_waitcnt vmcnt(0)" ::: "memory");
    }
    __builtin_amdgcn_sched_barrier(0);
    __builtin_amdgcn_s_barrier();     // all waves: cur tile complete
    __builtin_amdgcn_sched_barrier(0);
    if (ks < 30) GSTAGE(nxt);         // safe: all waves past reads of buf[nxt]

    const char* la = (const char*)Al[cur];
    const char* lb = (const char*)Bl[cur];
    bf16x8 a[4], b[4];
    #pragma unroll
    for (int m = 0; m < 4; ++m)
      a[m] = *(const bf16x8*)(la + (wr * 64 + m * 16 + c) * 64 + ch);
    #pragma unroll
    for (int n = 0; n < 4; ++n)
      b[n] = *(const bf16x8*)(lb + (wc * 64 + n * 16 + c) * 64 + ch);
    __builtin_amdgcn_s_setprio(1);
    #pragma unroll
    for (int m = 0; m < 4; ++m)
      #pragma unroll
      for (int n = 0; n < 4; ++n)
        acc[m][n] = __builtin_amdgcn_mfma_f32_16x16x32_bf16(a[m], b[n], acc[m][n], 0, 0, 0);
    __builtin_amdgcn_s_setprio(0);

    cur = (cur == 2) ? 0 : cur + 1;
    nxt = (nxt == 2) ? 0 : nxt + 1;
  }
#undef GSTAGE

  int sel = n0 >> 10;
  const float* bp = (sel == 0) ? bq : (sel == 1) ? bk : bv;
  float scl = (sel == 0) ? 0.125f * LOG2E : 1.0f;

  #pragma unroll
  for (int n = 0; n < 4; ++n) {
    int nn = (n0 & 1023) + wc * 64 + n * 16 + c;
    float bias = bp[nn];
    int h = nn >> 6, d = nn & 63;
    #pragma unroll
    for (int m = 0; m < 4; ++m) {
      int rowg = m0 + wr * 64 + m * 16 + g * 4;
      int bb = rowg >> 10;
      int s = rowg & 1023;
      #pragma unroll
      for (int r = 0; r < 4; ++r) {
        float val = (acc[m][n][r] + bias) * scl;
        unsigned short ob = f2bf(val);
        if (sel == 0)
          Q[(size_t)((bb * 16 + h) * 1024 + s + r) * 64 + d] = ob;
        else if (sel == 1)
          K[(size_t)((bb * 16 + h) * 1024 + s + r) * 64 + d] = ob;
        else
          Vt[(size_t)((bb * 16 + h) * 64 + d) * 1024 + s + r] = ob;
      }
    }
  }
}

// Build two PV A-fragments from 16 P values (C-layout) — 8 cvt_pk + 4
// permlane32_swap, no LDS.
__device__ __forceinline__ void build_pa(const f32x16& p, bf16x8& pa0, bf16x8& pa1) {
  unsigned W0 = cvtpk(p[0],  p[1]);
  unsigned W1 = cvtpk(p[2],  p[3]);
  unsigned W2 = cvtpk(p[4],  p[5]);
  unsigned W3 = cvtpk(p[6],  p[7]);
  unsigned W4 = cvtpk(p[8],  p[9]);
  unsigned W5 = cvtpk(p[10], p[11]);
  unsigned W6 = cvtpk(p[12], p[13]);
  unsigned W7 = cvtpk(p[14], p[15]);
  pl32swap(W0, W2);
  pl32swap(W1, W3);
  pl32swap(W4, W6);
  pl32swap(W5, W7);
  union { unsigned u[4]; bf16x8 v; } a0, a1;
  a0.u[0] = W0; a0.u[1] = W1; a0.u[2] = W2; a0.u[3] = W3;
  a1.u[0] = W4; a1.u[1] = W5; a1.u[2] = W6; a1.u[3] = W7;
  pa0 = a0.v; pa1 = a1.v;
}

// ---------------- flash attention, 32x32 swapped, 2 q-tiles/wave ----------
// 2-wave blocks (128 thr); each wave owns 64 q-rows = TWO 32x32 C-tiles.
// K/V/mask LDS reads loaded ONCE per iter feed both q-tiles (LDS reads per
// unit work halved). KV double-buffered (36 KB) -> 4 blocks/CU. 1 barrier/
// iter (R12-proven race-free skeleton).
__global__ __launch_bounds__(128, 2) void attn(
    const ushort* __restrict__ Q,    // [B*H][S][64], pre-scaled 0.125*log2e
    const ushort* __restrict__ K,    // [B*H][S][64]
    const ushort* __restrict__ Vt,   // [B*H][64][S]
    const float* __restrict__ mask,  // [B][S]
    float* __restrict__ out)         // [B][S][1024]
{
  __shared__ __attribute__((aligned(16))) char kv_lds[2][16384]; // [K 8K][V 8K] x2
  __shared__ float mask_s[SS];                                   // 4 KB (log2-domain)

  int blk = blockIdx.x;           // 512
  int xcd = blk & 7;
  int j = blk >> 3;               // 0..63
  int bh = xcd * 8 + (j >> 3);    // 8 heads per XCD; 8 blocks per head
  int qt = j & 7;
  int b = bh >> 4, h = bh & 15;
  int tid = threadIdx.x, wave = tid >> 6, lane = tid & 63;
  int r31 = lane & 31, hi = lane >> 5;
  int rsw = r31 & 7;
  int hib = hi << 4;
  int q0 = qt * 128 + wave * 64;  // wave owns q0..q0+63

  const ushort* Qb = Q + (size_t)bh * SS * 64;
  const ushort* Kb = K + (size_t)bh * SS * 64;
  const ushort* Vb = Vt + (size_t)bh * 64 * SS;

  // mask to LDS, pre-multiplied by log2e
  for (int i = tid; i < SS; i += 128) mask_s[i] = mask[b * SS + i] * LOG2E;

  bf16x8 qfA[4], qfB[4];
  #pragma unroll
  for (int kp = 0; kp < 4; ++kp) {
    qfA[kp] = *(const bf16x8*)(Qb + (size_t)(q0 + r31) * 64 + kp * 16 + hi * 8);
    qfB[kp] = *(const bf16x8*)(Qb + (size_t)(q0 + 32 + r31) * 64 + kp * 16 + hi * 8);
  }

  // staging: wave 0 -> K tile (8KB), wave 1 -> V tile (8KB); 8 loads/lane.
  // Instr i writes LDS row i*8+(lane>>3), pos lane&7; XOR bank swizzle via
  // GLOBAL chunk = pos ^ (row&7). Reads use same XOR.
  int srow = lane >> 3;           // 0..7 == row&7 for every instr
  int gck = (lane & 7) ^ srow;
  bool isK = (wave == 0);
  const ushort* sbase = isK
      ? (Kb + (size_t)srow * 64 + gck * 8)
      : (Vb + (size_t)srow * SS + gck * 8);
  const size_t sistep = isK ? (size_t)8 * 64 : (size_t)8 * SS;
  const int sadv = isK ? 64 * 64 : 64;
  int sldso = isK ? 0 : 8192;

#define STAGE(bufidx) do {                                  \
    char* lb_ = kv_lds[bufidx] + sldso;                     \
    _Pragma("unroll")                                       \
    for (int i_ = 0; i_ < 8; ++i_)                          \
      async16(lb_ + i_ * 1024 + lane * 16,                  \
              sbase + (size_t)i_ * sistep);                 \
    sbase += sadv;                                          \
  } while (0)

  STAGE(0);
  __syncthreads();                // tile0 + mask visible

  f32x16 oA0 = (f32x16)0.0f, oA1 = (f32x16)0.0f;
  f32x16 oB0 = (f32x16)0.0f, oB1 = (f32x16)0.0f;
  float mrowA = 0.f, lrowA = 0.f, mrowB = 0.f, lrowB = 0.f;

  int cur = 0;
  for (int it = 0; it < 16; ++it) {
    if (it < 15) STAGE(cur ^ 1);

    const char* kb0 = kv_lds[cur];
    const char* vb0 = kv_lds[cur] + 8192;

    // K fragments ONCE; feed both q-tiles
    bf16x8 ka[4], kc[4];
    #pragma unroll
    for (int kp = 0; kp < 4; ++kp) {
      int ch = (((kp << 1) | hi) ^ rsw) << 4;
      ka[kp] = *(const bf16x8*)(kb0 + r31 * 128 + ch);
      kc[kp] = *(const bf16x8*)(kb0 + (32 + r31) * 128 + ch);
    }
    f32x16 s0A = (f32x16)0.0f, s1A = (f32x16)0.0f;
    f32x16 s0B = (f32x16)0.0f, s1B = (f32x16)0.0f;
    __builtin_amdgcn_s_setprio(1);
    #pragma unroll
    for (int kp = 0; kp < 4; ++kp) {
      s0A = __builtin_amdgcn_mfma_f32_32x32x16_bf16(ka[kp], qfA[kp], s0A, 0, 0, 0);
      s1A = __builtin_amdgcn_mfma_f32_32x32x16_bf16(kc[kp], qfA[kp], s1A, 0, 0, 0);
      s0B = __builtin_amdgcn_mfma_f32_32x32x16_bf16(ka[kp], qfB[kp], s0B, 0, 0, 0);
      s1B = __builtin_amdgcn_mfma_f32_32x32x16_bf16(kc[kp], qfB[kp], s1B, 0, 0, 0);
    }
    __builtin_amdgcn_s_setprio(0);

    int kv = it * 64;
    #pragma unroll
    for (int sq = 0; sq < 4; ++sq) {
      f32x4 mk0 = *(const f32x4*)(&mask_s[kv + sq * 8 + hi * 4]);
      f32x4 mk1 = *(const f32x4*)(&mask_s[kv + 32 + sq * 8 + hi * 4]);
      #pragma unroll
      for (int r = 0; r < 4; ++r) {
        s0A[sq * 4 + r] += mk0[r]; s1A[sq * 4 + r] += mk1[r];
        s0B[sq * 4 + r] += mk0[r]; s1B[sq * 4 + r] += mk1[r];
      }
    }

    // ---- softmax tile A (stats for q = q0 + r31) ----
    float mxA = s0A[0];
    #pragma unroll
    for (int i = 1; i < 16; ++i) mxA = fmaxf(mxA, s0A[i]);
    #pragma unroll
    for (int i = 0; i < 16; ++i) mxA = fmaxf(mxA, s1A[i]);
    mxA = fmaxf(mxA, __shfl_xor(mxA, 32));
    if (!__all(mxA <= mrowA + 11.5416f)) {
      float mn = fmaxf(mrowA, mxA);
      float sc = exp2fast(mrowA - mn);
      mrowA = mn; lrowA *= sc;
      #pragma unroll
      for (int i = 0; i < 16; ++i) {
        int qh = (i & 3) + 8 * (i >> 2);
        float scq = __uint_as_float((unsigned)__builtin_amdgcn_ds_bpermute(
            (qh << 2) + hib, (int)__float_as_uint(sc)));
        oA0[i] *= scq; oA1[i] *= scq;
      }
    }
    float rsA = 0.f;
    #pragma unroll
    for (int i = 0; i < 16; ++i) { float e = exp2fast(s0A[i] - mrowA); s0A[i] = e; rsA += e; }
    #pragma unroll
    for (int i = 0; i < 16; ++i) { float e = exp2fast(s1A[i] - mrowA); s1A[i] = e; rsA += e; }
    rsA += __shfl_xor(rsA, 32);
    lrowA += rsA;

    // ---- softmax tile B (stats for q = q0 + 32 + r31) ----
    float mxB = s0B[0];
    #pragma unroll
    for (int i = 1; i < 16; ++i) mxB = fmaxf(mxB, s0B[i]);
    #pragma unroll
    for (int i = 0; i < 16; ++i) mxB = fmaxf(mxB, s1B[i]);
    mxB = fmaxf(mxB, __shfl_xor(mxB, 32));
    if (!__all(mxB <= mrowB + 11.5416f)) {
      float mn = fmaxf(mrowB, mxB);
      float sc = exp2fast(mrowB - mn);
      mrowB = mn; lrowB *= sc;
      #pragma unroll
      for (int i = 0; i < 16; ++i) {
        int qh = (i & 3) + 8 * (i >> 2);
        float scq = __uint_as_float((unsigned)__builtin_amdgcn_ds_bpermute(
            (qh << 2) + hib, (int)__float_as_uint(sc)));
        oB0[i] *= scq; oB1[i] *= scq;
      }
    }
    float rsB = 0.f;
    #pragma unroll
    for (int i = 0; i < 16; ++i) { float e = exp2fast(s0B[i] - mrowB); s0B[i] = e; rsB += e; }
    #pragma unroll
    for (int i = 0; i < 16; ++i) { float e = exp2fast(s1B[i] - mrowB); s1B[i] = e; rsB += e; }
    rsB += __shfl_xor(rsB, 32);
    lrowB += rsB;

    // V fragments ONCE; feed both q-tiles
    bf16x8 va[4], vc[4];
    #pragma unroll
    for (int kap = 0; kap < 4; ++kap) {
      int ch = (((kap << 1) | hi) ^ rsw) << 4;
      va[kap] = *(const bf16x8*)(vb0 + r31 * 128 + ch);
      vc[kap] = *(const bf16x8*)(vb0 + (32 + r31) * 128 + ch);
    }

    #pragma unroll
    for (int T = 0; T < 2; ++T) {
      bf16x8 paA0, paA1, paB0, paB1;
      build_pa(T ? s1A : s0A, paA0, paA1);
      build_pa(T ? s1B : s0B, paB0, paB1);
      __builtin_amdgcn_s_setprio(1);
      #pragma unroll
      for (int kh = 0; kh < 2; ++kh) {
        int kap = 2 * T + kh;
        bf16x8 pfA = kh ? paA1 : paA0;
        bf16x8 pfB = kh ? paB1 : paB0;
        oA0 = __builtin_amdgcn_mfma_f32_32x32x16_bf16(pfA, va[kap], oA0, 0, 0, 0);
        oA1 = __builtin_amdgcn_mfma_f32_32x32x16_bf16(pfA, vc[kap], oA1, 0, 0, 0);
        oB0 = __builtin_amdgcn_mfma_f32_32x32x16_bf16(pfB, va[kap], oB0, 0, 0, 0);
        oB1 = __builtin_amdgcn_mfma_f32_32x32x16_bf16(pfB, vc[kap], oB1, 0, 0, 0);
      }
      __builtin_amdgcn_s_setprio(0);
    }

    // end-of-iter: stage loads landed AND both waves done reading buf[cur].
    asm volatile("s_waitcnt vmcnt(0)" ::: "memory");
    __builtin_amdgcn_sched_barrier(0);
    __builtin_amdgcn_s_barrier();
    __builtin_amdgcn_sched_barrier(0);
    cur ^= 1;
  }
#undef STAGE

  float invA = 1.0f / lrowA, invB = 1.0f / lrowB;
  #pragma unroll
  for (int i = 0; i < 16; ++i) {
    int qh = (i & 3) + 8 * (i >> 2);
    float liA = __uint_as_float((unsigned)__builtin_amdgcn_ds_bpermute(
        (qh << 2) + hib, (int)__float_as_uint(invA)));
    float liB = __uint_as_float((unsigned)__builtin_amdgcn_ds_bpermute(
        (qh << 2) + hib, (int)__float_as_uint(invB)));
    int rowA = q0 + qh + 4 * hi;
    float* opA = out + (size_t)(b * SS + rowA) * 1024 + h * 64 + r31;
    opA[0]  = oA0[i] * liA;
    opA[32] = oA1[i] * liA;
    float* opB = out + (size_t)(b * SS + rowA + 32) * 1024 + h * 64 + r31;
    opB[0]  = oB0[i] * liB;
    opB[32] = oB1[i] * liB;
  }
}

extern "C" void kernel_launch(void* const* d_in, const int* in_sizes, int n_in,
                              void* d_out, int out_size, void* d_ws, size_t ws_size,
                              hipStream_t stream) {
  const float* hs   = (const float*)d_in[0];
  const float* mask = (const float*)d_in[1];
  const float* Wq   = (const float*)d_in[2];
  const float* bq   = (const float*)d_in[3];
  const float* Wk   = (const float*)d_in[4];
  const float* bk   = (const float*)d_in[5];
  const float* Wv   = (const float*)d_in[6];
  const float* bv   = (const float*)d_in[7];
  float* out = (float*)d_out;

  char* ws = (char*)d_ws;
  ushort* Xb = (ushort*)(ws);                    // 8 MB  [4096][1024]
  ushort* Wb = (ushort*)(ws + (8u  << 20));      // 6 MB  [3072][1024]
  ushort* Qp = (ushort*)(ws + (14u << 20));      // 8 MB  [64][1024][64]
  ushort* Kp = (ushort*)(ws + (22u << 20));      // 8 MB  [64][1024][64]
  ushort* Vt = (ushort*)(ws + (30u << 20));      // 8 MB  [64][64][1024]

  cvt_all<<<7168, 256, 0, stream>>>((const float4*)hs, (const float4*)Wq,
                                    (const float4*)Wk, (const float4*)Wv,
                                    (ushort4*)Xb, (ushort4*)Wb);
  qkv_gemm<<<768, 256, 0, stream>>>(Xb, Wb, bq, bk, bv, Qp, Kp, Vt);
  attn<<<512, 128, 0, stream>>>(Qp, Kp, Vt, mask, out);
}

// Round 14
// 85.544 us; speedup vs baseline: 1.1823x; 1.1823x over previous
//
#include <hip/hip_runtime.h>
#include <hip/hip_bf16.h>
#include <stdint.h>

#define NH 16
#define HID 1024
#define HD 64
#define NB 4
#define SS 1024
#define MTOT (NB*SS)   // 4096

typedef __attribute__((ext_vector_type(8))) short bf16x8;
typedef __attribute__((ext_vector_type(4))) float f32x4;
typedef __attribute__((ext_vector_type(16))) float f32x16;

#define LOG2E 1.44269504088896f

__device__ __forceinline__ unsigned short f2bf(float f) {
  union { float f; unsigned u; } v; v.f = f;
  unsigned u = v.u;
  return (unsigned short)((u + 0x7FFFu + ((u >> 16) & 1u)) >> 16);
}

__device__ __forceinline__ unsigned cvtpk(float lo, float hi) {
  unsigned r;
  asm("v_cvt_pk_bf16_f32 %0, %1, %2" : "=v"(r) : "v"(lo), "v"(hi));
  return r;
}

__device__ __forceinline__ void pl32swap(unsigned &a, unsigned &b) {
  asm("v_permlane32_swap_b32 %0, %1" : "+v"(a), "+v"(b));
}

__device__ __forceinline__ float exp2fast(float x) {
  float r;
  asm("v_exp_f32 %0, %1" : "=v"(r) : "v"(x));
  return r;
}

__device__ __forceinline__ void async16(void* lds, const void* g) {
  __builtin_amdgcn_global_load_lds(
      (const __attribute__((address_space(1))) unsigned*)g,
      (__attribute__((address_space(3))) unsigned*)lds, 16, 0, 0);
}

// ---------------- fp32 -> bf16 conversion of X and W ----------------
__global__ void cvt_all(const float4* __restrict__ X,
                        const float4* __restrict__ Wq,
                        const float4* __restrict__ Wk,
                        const float4* __restrict__ Wv,
                        ushort4* __restrict__ Xb,
                        ushort4* __restrict__ Wb) {
  int i = blockIdx.x * 256 + threadIdx.x;   // 1835008 total
  const float4* src; ushort4* dst; int idx;
  if (i < (MTOT * HID / 4)) {
    src = X; dst = Xb; idx = i;
  } else {
    int j = i - (MTOT * HID / 4);
    int sel = j >> 18;
    idx = j & 262143;
    src = (sel == 0) ? Wq : (sel == 1) ? Wk : Wv;
    dst = Wb + (size_t)sel * 262144;
  }
  float4 v = src[idx];
  ushort4 o;
  o.x = f2bf(v.x); o.y = f2bf(v.y); o.z = f2bf(v.z); o.w = f2bf(v.w);
  dst[idx] = o;
}

// ---------------- fused QKV projection GEMM (R6 config, proven 45.5us) ----
// BK=32 TRIPLE-buffered, 1 barrier/step, STAGE after barrier, counted vmcnt.
// Q pre-scaled by 0.125*log2(e) so attention softmax runs in exp2 domain.
__global__ __launch_bounds__(256) void qkv_gemm(
    const ushort* __restrict__ Xb,    // [4096][1024] bf16
    const ushort* __restrict__ Wb,    // [3072][1024] bf16 (Wq|Wk|Wv)
    const float* __restrict__ bq,
    const float* __restrict__ bk,
    const float* __restrict__ bv,
    ushort* __restrict__ Q,           // [B*H][S][64]
    ushort* __restrict__ K,           // [B*H][S][64]
    ushort* __restrict__ Vt)          // [B*H][64][S]
{
  __shared__ __attribute__((aligned(16))) ushort Al[3][128 * 32]; // 3x8KB
  __shared__ __attribute__((aligned(16))) ushort Bl[3][128 * 32]; // 3x8KB

  int bid = blockIdx.x;               // 768 blocks
  int swz = (bid & 7) * 96 + (bid >> 3);  // XCD swizzle (768 % 8 == 0)
  const int nbn = 3072 / 128;         // 24
  int bm = swz / nbn, bn = swz % nbn;
  int m0 = bm * 128, n0 = bn * 128;

  int tid = threadIdx.x;
  int wave = tid >> 6, lane = tid & 63;
  int g = lane >> 4, c = lane & 15;
  int wr = wave >> 1, wc = wave & 1;  // 2x2 waves, each 64x64 output

  // staging: per K-step each thread issues 2 A-loads + 2 B-loads (16B).
  // LDS dest linear; bank swizzle via XOR on the GLOBAL 16B-chunk index.
  int srow = tid >> 2;                // 0..63
  int schunk = tid & 3;
  int ssw = (srow >> 1) & 3;
  const ushort* Asrc0 = Xb + (size_t)(m0 + srow) * 1024 + ((schunk ^ ssw) << 3);
  const ushort* Asrc1 = Xb + (size_t)(m0 + 64 + srow) * 1024 + ((schunk ^ ssw) << 3);
  const ushort* Bsrc0 = Wb + (size_t)(n0 + srow) * 1024 + ((schunk ^ ssw) << 3);
  const ushort* Bsrc1 = Wb + (size_t)(n0 + 64 + srow) * 1024 + ((schunk ^ ssw) << 3);
  int soff = srow * 64 + schunk * 16;

#define GSTAGE(bi) do {                                   \
    char* la_ = (char*)Al[bi]; char* lb_ = (char*)Bl[bi]; \
    async16(la_ + soff,        Asrc0);                    \
    async16(la_ + 4096 + soff, Asrc1);                    \
    async16(lb_ + soff,        Bsrc0);                    \
    async16(lb_ + 4096 + soff, Bsrc1);                    \
    Asrc0 += 32; Asrc1 += 32; Bsrc0 += 32; Bsrc1 += 32;   \
  } while (0)

  f32x4 acc[4][4] = {};
  int rsw = (c >> 1) & 3;             // read-side swizzle
  int ch = ((g ^ rsw) << 4);          // swizzled 16B chunk byte offset

  GSTAGE(0);                          // prologue: 2 steps in flight
  GSTAGE(1);

  int cur = 0, nxt = 2;
  for (int ks = 0; ks < 32; ++ks) {
    if (ks < 31) {
      asm volatile("s_waitcnt vmcnt(4)" ::: "memory");  // cur landed, next in flight
    } else {
      asm volatile("s_waitcnt vmcnt(0)" ::: "memory");
    }
    __builtin_amdgcn_sched_barrier(0);
    __builtin_amdgcn_s_barrier();     // all waves: cur tile complete
    __builtin_amdgcn_sched_barrier(0);
    if (ks < 30) GSTAGE(nxt);         // safe: all waves past reads of buf[nxt]

    const char* la = (const char*)Al[cur];
    const char* lb = (const char*)Bl[cur];
    bf16x8 a[4], b[4];
    #pragma unroll
    for (int m = 0; m < 4; ++m)
      a[m] = *(const bf16x8*)(la + (wr * 64 + m * 16 + c) * 64 + ch);
    #pragma unroll
    for (int n = 0; n < 4; ++n)
      b[n] = *(const bf16x8*)(lb + (wc * 64 + n * 16 + c) * 64 + ch);
    __builtin_amdgcn_s_setprio(1);
    #pragma unroll
    for (int m = 0; m < 4; ++m)
      #pragma unroll
      for (int n = 0; n < 4; ++n)
        acc[m][n] = __builtin_amdgcn_mfma_f32_16x16x32_bf16(a[m], b[n], acc[m][n], 0, 0, 0);
    __builtin_amdgcn_s_setprio(0);

    cur = (cur == 2) ? 0 : cur + 1;
    nxt = (nxt == 2) ? 0 : nxt + 1;
  }
#undef GSTAGE

  int sel = n0 >> 10;
  const float* bp = (sel == 0) ? bq : (sel == 1) ? bk : bv;
  float scl = (sel == 0) ? 0.125f * LOG2E : 1.0f;

  #pragma unroll
  for (int n = 0; n < 4; ++n) {
    int nn = (n0 & 1023) + wc * 64 + n * 16 + c;
    float bias = bp[nn];
    int h = nn >> 6, d = nn & 63;
    #pragma unroll
    for (int m = 0; m < 4; ++m) {
      int rowg = m0 + wr * 64 + m * 16 + g * 4;
      int bb = rowg >> 10;
      int s = rowg & 1023;
      #pragma unroll
      for (int r = 0; r < 4; ++r) {
        float val = (acc[m][n][r] + bias) * scl;
        unsigned short ob = f2bf(val);
        if (sel == 0)
          Q[(size_t)((bb * 16 + h) * 1024 + s + r) * 64 + d] = ob;
        else if (sel == 1)
          K[(size_t)((bb * 16 + h) * 1024 + s + r) * 64 + d] = ob;
        else
          Vt[(size_t)((bb * 16 + h) * 64 + d) * 1024 + s + r] = ob;
      }
    }
  }
}

// Build two PV A-fragments from 16 P values (C-layout) — 8 cvt_pk + 4
// permlane32_swap, no LDS.
__device__ __forceinline__ void build_pa(const f32x16& p, bf16x8& pa0, bf16x8& pa1) {
  unsigned W0 = cvtpk(p[0],  p[1]);
  unsigned W1 = cvtpk(p[2],  p[3]);
  unsigned W2 = cvtpk(p[4],  p[5]);
  unsigned W3 = cvtpk(p[6],  p[7]);
  unsigned W4 = cvtpk(p[8],  p[9]);
  unsigned W5 = cvtpk(p[10], p[11]);
  unsigned W6 = cvtpk(p[12], p[13]);
  unsigned W7 = cvtpk(p[14], p[15]);
  pl32swap(W0, W2);
  pl32swap(W1, W3);
  pl32swap(W4, W6);
  pl32swap(W5, W7);
  union { unsigned u[4]; bf16x8 v; } a0, a1;
  a0.u[0] = W0; a0.u[1] = W1; a0.u[2] = W2; a0.u[3] = W3;
  a1.u[0] = W4; a1.u[1] = W5; a1.u[2] = W6; a1.u[3] = W7;
  pa0 = a0.v; pa1 = a1.v;
}

// ---------------- flash attention, 32x32 swapped orientation ----------------
// 512-thread blocks: 8 waves x 32 q-rows = 256 q-rows/block; grid 256 =
// EXACTLY 1 block/CU. K/V tile (16KB/iter) amortized over 2x the q-rows;
// staging = 2 loads/thread. Triple-buffered, 1 barrier/iter, counted vmcnt.
__global__ __launch_bounds__(512) void attn(
    const ushort* __restrict__ Q,    // [B*H][S][64], pre-scaled 0.125*log2e
    const ushort* __restrict__ K,    // [B*H][S][64]
    const ushort* __restrict__ Vt,   // [B*H][64][S]
    const float* __restrict__ mask,  // [B][S]
    float* __restrict__ out)         // [B][S][1024]
{
  __shared__ __attribute__((aligned(16))) char kv_lds[3][16384]; // [K 8K][V 8K] x3
  __shared__ float mask_s[SS];                                   // 4 KB (log2-domain)

  int blk = blockIdx.x;           // 256
  int xcd = blk & 7;
  int j = blk >> 3;               // 0..31
  int bh = xcd * 8 + (j >> 2);    // 8 heads per XCD; 4 blocks per head
  int qt = j & 3;
  int b = bh >> 4, h = bh & 15;
  int tid = threadIdx.x, wave = tid >> 6, lane = tid & 63;
  int r31 = lane & 31, hi = lane >> 5;
  int rsw = r31 & 7;
  int hib = hi << 4;
  int q0 = qt * 256 + wave * 32;

  const ushort* Qb = Q + (size_t)bh * SS * 64;
  const ushort* Kb = K + (size_t)bh * SS * 64;
  const ushort* Vb = Vt + (size_t)bh * 64 * SS;

  // mask to LDS, pre-multiplied by log2e (off the vmcnt path in the loop)
  for (int i = tid; i < SS; i += 512) mask_s[i] = mask[b * SS + i] * LOG2E;

  bf16x8 qf[4];
  #pragma unroll
  for (int kp = 0; kp < 4; ++kp)
    qf[kp] = *(const bf16x8*)(Qb + (size_t)(q0 + r31) * 64 + kp * 16 + hi * 8);

  // staging: waves 0-3 -> K tile (8KB), waves 4-7 -> V tile (8KB).
  // 2 x 16B loads per thread. LDS dest linear; XOR bank swizzle via the
  // GLOBAL chunk index (chunk' = chunk ^ (row&7)); reads use same XOR.
  int srow = lane >> 3;           // 0..7
  int spos = lane & 7;
  bool isK = (wave < 4);
  int w4 = isK ? wave : wave - 4;
  const ushort* sptr[2];
  int soff[2];
  #pragma unroll
  for (int j2 = 0; j2 < 2; ++j2) {
    int row = w4 * 16 + j2 * 8 + srow;                 // 0..63
    soff[j2] = (isK ? 0 : 8192) + w4 * 2048 + j2 * 1024 + lane * 16;
    if (isK)
      sptr[j2] = Kb + (size_t)row * 64 + ((spos ^ srow) << 3);
    else
      sptr[j2] = Vb + (size_t)row * SS + ((spos ^ srow) << 3);
  }
  const int sstep = isK ? 64 * 64 : 64;

#define STAGE(bufidx) do {                              \
    char* lb_ = kv_lds[bufidx];                         \
    async16(lb_ + soff[0], sptr[0]);                    \
    async16(lb_ + soff[1], sptr[1]);                    \
    sptr[0] += sstep; sptr[1] += sstep;                 \
  } while (0)

  __syncthreads();                // mask_s visible to all waves
  STAGE(0);                       // prologue: 2 tiles in flight
  STAGE(1);

  f32x16 o0 = (f32x16)0.0f, o1 = (f32x16)0.0f;
  float mrow = 0.f, lrow = 0.f;

  int cur = 0, nxt = 2;
  for (int it = 0; it < 16; ++it) {
    if (it < 15) {
      asm volatile("s_waitcnt vmcnt(2)" ::: "memory");
    } else {
      asm volatile("s_waitcnt vmcnt(0)" ::: "memory");
    }
    __builtin_amdgcn_sched_barrier(0);
    __builtin_amdgcn_s_barrier();
    __builtin_amdgcn_sched_barrier(0);
    if (it < 14) STAGE(nxt);

    const char* kb0 = kv_lds[cur];
    const char* vb0 = kv_lds[cur] + 8192;

    f32x16 s0 = (f32x16)0.0f, s1 = (f32x16)0.0f;
    __builtin_amdgcn_s_setprio(1);
    #pragma unroll
    for (int kp = 0; kp < 4; ++kp) {
      int ch = (((kp << 1) | hi) ^ rsw) << 4;
      bf16x8 ka = *(const bf16x8*)(kb0 + r31 * 128 + ch);
      bf16x8 kc = *(const bf16x8*)(kb0 + (32 + r31) * 128 + ch);
      s0 = __builtin_amdgcn_mfma_f32_32x32x16_bf16(ka, qf[kp], s0, 0, 0, 0);
      s1 = __builtin_amdgcn_mfma_f32_32x32x16_bf16(kc, qf[kp], s1, 0, 0, 0);
    }
    __builtin_amdgcn_s_setprio(0);

    int kv = it * 64;
    #pragma unroll
    for (int sq = 0; sq < 4; ++sq) {
      f32x4 mk0 = *(const f32x4*)(&mask_s[kv + sq * 8 + hi * 4]);
      f32x4 mk1 = *(const f32x4*)(&mask_s[kv + 32 + sq * 8 + hi * 4]);
      #pragma unroll
      for (int r = 0; r < 4; ++r) {
        s0[sq * 4 + r] += mk0[r];
        s1[sq * 4 + r] += mk1[r];
      }
    }

    float mx = s0[0];
    #pragma unroll
    for (int i = 1; i < 16; ++i) mx = fmaxf(mx, s0[i]);
    #pragma unroll
    for (int i = 0; i < 16; ++i) mx = fmaxf(mx, s1[i]);
    mx = fmaxf(mx, __shfl_xor(mx, 32));

    if (!__all(mx <= mrow + 11.5416f)) {   // defer-max
      float mn = fmaxf(mrow, mx);
      float sc = exp2fast(mrow - mn);
      mrow = mn;
      lrow *= sc;
      #pragma unroll
      for (int i = 0; i < 16; ++i) {
        int qh = (i & 3) + 8 * (i >> 2);
        float scq = __uint_as_float((unsigned)__builtin_amdgcn_ds_bpermute(
            (qh << 2) + hib, (int)__float_as_uint(sc)));
        o0[i] *= scq; o1[i] *= scq;
      }
    }

    f32x16 p0, p1;
    float rs = 0.f;
    #pragma unroll
    for (int i = 0; i < 16; ++i) { float e = exp2fast(s0[i] - mrow); p0[i] = e; rs += e; }
    #pragma unroll
    for (int i = 0; i < 16; ++i) { float e = exp2fast(s1[i] - mrow); p1[i] = e; rs += e; }
    rs += __shfl_xor(rs, 32);
    lrow += rs;

    #pragma unroll
    for (int T = 0; T < 2; ++T) {
      bf16x8 pa0, pa1;
      build_pa(T ? p1 : p0, pa0, pa1);
      __builtin_amdgcn_s_setprio(1);
      #pragma unroll
      for (int kh = 0; kh < 2; ++kh) {
        int kap = 2 * T + kh;
        int ch = (((kap << 1) | hi) ^ rsw) << 4;
        bf16x8 va = *(const bf16x8*)(vb0 + r31 * 128 + ch);
        bf16x8 vc = *(const bf16x8*)(vb0 + (32 + r31) * 128 + ch);
        bf16x8 pf = kh ? pa1 : pa0;
        o0 = __builtin_amdgcn_mfma_f32_32x32x16_bf16(pf, va, o0, 0, 0, 0);
        o1 = __builtin_amdgcn_mfma_f32_32x32x16_bf16(pf, vc, o1, 0, 0, 0);
      }
      __builtin_amdgcn_s_setprio(0);
    }

    cur = (cur == 2) ? 0 : cur + 1;
    nxt = (nxt == 2) ? 0 : nxt + 1;
  }
#undef STAGE

  float inv = 1.0f / lrow;
  #pragma unroll
  for (int i = 0; i < 16; ++i) {
    int qh = (i & 3) + 8 * (i >> 2);
    float li = __uint_as_float((unsigned)__builtin_amdgcn_ds_bpermute(
        (qh << 2) + hib, (int)__float_as_uint(inv)));
    int row = q0 + qh + 4 * hi;
    float* op = out + (size_t)(b * SS + row) * 1024 + h * 64 + r31;
    op[0]  = o0[i] * li;
    op[32] = o1[i] * li;
  }
}

extern "C" void kernel_launch(void* const* d_in, const int* in_sizes, int n_in,
                              void* d_out, int out_size, void* d_ws, size_t ws_size,
                              hipStream_t stream) {
  const float* hs   = (const float*)d_in[0];
  const float* mask = (const float*)d_in[1];
  const float* Wq   = (const float*)d_in[2];
  const float* bq   = (const float*)d_in[3];
  const float* Wk   = (const float*)d_in[4];
  const float* bk   = (const float*)d_in[5];
  const float* Wv   = (const float*)d_in[6];
  const float* bv   = (const float*)d_in[7];
  float* out = (float*)d_out;

  char* ws = (char*)d_ws;
  ushort* Xb = (ushort*)(ws);                    // 8 MB  [4096][1024]
  ushort* Wb = (ushort*)(ws + (8u  << 20));      // 6 MB  [3072][1024]
  ushort* Qp = (ushort*)(ws + (14u << 20));      // 8 MB  [64][1024][64]
  ushort* Kp = (ushort*)(ws + (22u << 20));      // 8 MB  [64][1024][64]
  ushort* Vt = (ushort*)(ws + (30u << 20));      // 8 MB  [64][64][1024]

  cvt_all<<<7168, 256, 0, stream>>>((const float4*)hs, (const float4*)Wq,
                                    (const float4*)Wk, (const float4*)Wv,
                                    (ushort4*)Xb, (ushort4*)Wb);
  qkv_gemm<<<768, 256, 0, stream>>>(Xb, Wb, bq, bk, bv, Qp, Kp, Vt);
  attn<<<256, 512, 0, stream>>>(Qp, Kp, Vt, mask, out);
}